// Round 2
// baseline (1065.918 us; speedup 1.0000x reference)
//
#include <hip/hip_runtime.h>
#include <hip/hip_bf16.h>

typedef float f32x4 __attribute__((ext_vector_type(4)));
typedef short bf16x8 __attribute__((ext_vector_type(8)));
typedef unsigned short u16;
typedef unsigned short u16x4 __attribute__((ext_vector_type(4)));

#define HDIM 128
#define NNODES 100000
#define NEDGES 500000

// workspace layout (bytes)
#define WT_OFF   0                       // 12 x 128x128 bf16 transposed weights
#define P1_OFF   393216
#define P2_OFF   (P1_OFF + 25600000)
#define Q_OFF    (P2_OFF + 25600000)
#define SUMS_OFF (Q_OFF + 25600000)
#define CNT_OFF  (SUMS_OFF + 51200000)

__device__ __forceinline__ u16 f2bf(float f) {
  unsigned int u = __builtin_bit_cast(unsigned int, f);
  u += 0x7fffu + ((u >> 16) & 1u);   // RNE
  return (u16)(u >> 16);
}
__device__ __forceinline__ float bf2f(u16 h) {
  unsigned int u = ((unsigned int)h) << 16;
  return __builtin_bit_cast(float, u);
}

// swizzled LDS addressing: row stride 256B, XOR byte-bits 4-6 with row&7
// (keeps ds_read_b128 fragment reads <=2-way bank conflicts; bijective per row)
__device__ __forceinline__ u16* lds_at(u16* base, int row, int colBytes) {
  return (u16*)((char*)base + row * 256 + (colBytes ^ ((row & 7) << 4)));
}

// cooperative: stage one 128x128 bf16 weight (already transposed: WT[n][k]) into LDS
__device__ __forceinline__ void stage_weight(const u16* __restrict__ wsrc, u16* wb, int tid) {
#pragma unroll
  for (int i = 0; i < 8; ++i) {
    int q = tid + 256 * i;          // 2048 chunks of 16B
    int r = q >> 4, c = q & 15;
    uint4 v = *(const uint4*)(wsrc + r * 128 + c * 8);
    *(uint4*)lds_at(wb, r, c * 16) = v;
  }
}

// one wave computes [16 rows x 128 cols] += A(16x128,bf16 LDS) * W(128x128,bf16 LDS)
// A-frag: lane l elem j = A[l&15][ks*32 + 8*(l>>4)+j]; B-frag from WT[n][k] (contig k)
// C-frag: acc[nt][j] = D[(l>>4)*4+j][nt*16 + (l&15)]
__device__ __forceinline__ void wave_gemm(u16* aBuf, u16* wb, f32x4* acc, int lane, int wv) {
  const int arow = 16 * wv + (lane & 15);
  const int kg = (lane >> 4) * 16;  // byte offset of k-group
#pragma unroll
  for (int ks = 0; ks < 4; ++ks) {
    bf16x8 a = *(const bf16x8*)lds_at(aBuf, arow, ks * 64 + kg);
#pragma unroll
    for (int nt = 0; nt < 8; ++nt) {
      bf16x8 b = *(const bf16x8*)lds_at(wb, nt * 16 + (lane & 15), ks * 64 + kg);
      acc[nt] = __builtin_amdgcn_mfma_f32_16x16x32_bf16(a, b, acc[nt], 0, 0, 0);
    }
  }
}

// ---------------- weight prep: transpose + bf16 ----------------
__global__ __launch_bounds__(256) void k_prep(
    const float* __restrict__ ew1, const float* __restrict__ ew2,
    const float* __restrict__ pw1, const float* __restrict__ pw2,
    const float* __restrict__ gw1, const float* __restrict__ gw2,
    const float* __restrict__ bw1, const float* __restrict__ bw2,
    u16* __restrict__ WT) {
  int m = blockIdx.x;
  const float* src; int k0 = 0;
  switch (m) {
    case 0: src = ew1; k0 = 0;   break;
    case 1: src = ew1; k0 = 128; break;
    case 2: src = ew1; k0 = 256; break;
    case 3: src = ew2; break;
    case 4: src = pw1; break;
    case 5: src = pw1; k0 = 128; break;
    case 6: src = pw2; break;
    case 7: src = gw1; break;
    case 8: src = gw1; k0 = 128; break;
    case 9: src = gw2; break;
    case 10: src = bw1; break;
    default: src = bw2; break;
  }
  for (int i = 0; i < 64; ++i) {
    int idx = threadIdx.x + 256 * i;
    int n = idx & 127, k = idx >> 7;
    WT[m * 16384 + n * 128 + k] = f2bf(src[(k0 + k) * 128 + n]);
  }
}

// ---------------- node pre: P1 = x@ew1_a + eb1, P2 = x@ew1_b, Q = x@pw1_a + pb1 ----
__global__ __launch_bounds__(256) void k_node_pre(
    const float* __restrict__ x, const u16* __restrict__ WT,
    const float* __restrict__ eb1, const float* __restrict__ pb1,
    u16* __restrict__ P1, u16* __restrict__ P2, u16* __restrict__ Qm) {
  __shared__ u16 smem[32768];
  u16* wb = smem; u16* bufX = smem + 16384; u16* bufO = smem + 24576;
  const int tid = threadIdx.x, lane = tid & 63, wv = tid >> 6;
  const int nbase = blockIdx.x * 64 + 16 * wv;
  // stage x (own 16 rows) -> bf16
#pragma unroll
  for (int i = 0; i < 8; ++i) {
    int q = lane + 64 * i; int r = q >> 5, c4 = q & 31; int n = nbase + r;
    float4 v = make_float4(0.f, 0.f, 0.f, 0.f);
    if (n < NNODES) v = *(const float4*)(x + (size_t)n * HDIM + c4 * 4);
    u16x4 h = { f2bf(v.x), f2bf(v.y), f2bf(v.z), f2bf(v.w) };
    *(u16x4*)lds_at(bufX, 16 * wv + r, c4 * 8) = h;
  }
#pragma unroll 1
  for (int job = 0; job < 3; ++job) {
    int m = (job == 0) ? 0 : (job == 1) ? 1 : 4;
    const float* bias = (job == 0) ? eb1 : (job == 1) ? nullptr : pb1;
    u16* out = (job == 0) ? P1 : (job == 1) ? P2 : Qm;
    __syncthreads();
    stage_weight(WT + m * 16384, wb, tid);
    __syncthreads();
    f32x4 acc[8] = {};
    wave_gemm(bufX, wb, acc, lane, wv);
#pragma unroll
    for (int nt = 0; nt < 8; ++nt) {
      int col = nt * 16 + (lane & 15);
      float bv = bias ? bias[col] : 0.0f;
#pragma unroll
      for (int j = 0; j < 4; ++j) {
        int r = 4 * (lane >> 4) + j;
        *lds_at(bufO, 16 * wv + r, col * 2) = f2bf(acc[nt][j] + bv);
      }
    }
#pragma unroll
    for (int i = 0; i < 4; ++i) {
      int q = lane + 64 * i; int r = q >> 4, c = q & 15; int n = nbase + r;
      if (n < NNODES)
        *(bf16x8*)(out + (size_t)n * HDIM + c * 8) =
            *(const bf16x8*)lds_at(bufO, 16 * wv + r, c * 16);
    }
  }
}

// ---------------- edge kernel: 3 chained GEMMs + scatter ----------------
__global__ __launch_bounds__(256) void k_edge(
    const float* __restrict__ attr, const int* __restrict__ eidx,
    const u16* __restrict__ WT, const u16* __restrict__ P1,
    const u16* __restrict__ P2, const u16* __restrict__ Qm,
    const float* __restrict__ eb2, float* __restrict__ sums,
    float* __restrict__ counts, float* __restrict__ outNE) {
  __shared__ u16 smem[32768];
  u16* wb = smem; u16* bufA = smem + 16384; u16* bufH = smem + 24576;
  const int tid = threadIdx.x, lane = tid & 63, wv = tid >> 6;
  const int e0 = blockIdx.x * 64;
  const int ebase = e0 + 16 * wv;
  if (tid < 64 && e0 + tid < NEDGES) atomicAdd(&counts[eidx[e0 + tid]], 1.0f);
  // stage edge_attr (own 16 rows) f32 -> bf16
#pragma unroll
  for (int i = 0; i < 8; ++i) {
    int q = lane + 64 * i; int r = q >> 5, c4 = q & 31; int e = ebase + r;
    float4 v = make_float4(0.f, 0.f, 0.f, 0.f);
    if (e < NEDGES) v = *(const float4*)(attr + (size_t)e * HDIM + c4 * 4);
    u16x4 h = { f2bf(v.x), f2bf(v.y), f2bf(v.z), f2bf(v.w) };
    *(u16x4*)lds_at(bufA, 16 * wv + r, c4 * 8) = h;
  }
  stage_weight(WT + 2 * 16384, wb, tid);   // ew1_c^T
  __syncthreads();
  f32x4 acc[8] = {};
  wave_gemm(bufA, wb, acc, lane, wv);      // A1 = attr @ ew1_c
  // gather PP = P1[row] + P2[col] (includes eb1) into bufH (own rows)
#pragma unroll
  for (int i = 0; i < 4; ++i) {
    int q = lane + 64 * i; int r = q >> 4, cc = (q & 15) * 8; int e = ebase + r;
    bf16x8 res = {};
    if (e < NEDGES) {
      int rid = eidx[e], cid = eidx[NEDGES + e];
      bf16x8 a = *(const bf16x8*)(P1 + (size_t)rid * HDIM + cc);
      bf16x8 b = *(const bf16x8*)(P2 + (size_t)cid * HDIM + cc);
#pragma unroll
      for (int k = 0; k < 8; ++k)
        res[k] = (short)f2bf(bf2f((u16)a[k]) + bf2f((u16)b[k]));
    }
    *(bf16x8*)lds_at(bufH, 16 * wv + r, cc * 2) = res;
  }
  // epilogue 1: h1 = relu(A1 + PP) -> bufH (bf16)
#pragma unroll
  for (int nt = 0; nt < 8; ++nt) {
#pragma unroll
    for (int j = 0; j < 4; ++j) {
      int r = 4 * (lane >> 4) + j; int cb = (nt * 16 + (lane & 15)) * 2;
      u16* p = lds_at(bufH, 16 * wv + r, cb);
      float v = acc[nt][j] + bf2f(*p);
      *p = f2bf(fmaxf(v, 0.0f));
    }
  }
  __syncthreads();
  stage_weight(WT + 3 * 16384, wb, tid);   // ew2^T
  __syncthreads();
#pragma unroll
  for (int t = 0; t < 8; ++t) acc[t] = (f32x4){0.f, 0.f, 0.f, 0.f};
  wave_gemm(bufH, wb, acc, lane, wv);      // ne = h1 @ ew2
  // epilogue 2: ne += eb2; write f32 to out, bf16 to bufA
#pragma unroll
  for (int nt = 0; nt < 8; ++nt) {
    int col = nt * 16 + (lane & 15);
    float bias = eb2[col];
#pragma unroll
    for (int j = 0; j < 4; ++j) {
      int r = 4 * (lane >> 4) + j; int e = ebase + r;
      float v = acc[nt][j] + bias;
      *lds_at(bufA, 16 * wv + r, col * 2) = f2bf(v);
      if (e < NEDGES) outNE[(size_t)e * HDIM + col] = v;
    }
  }
  // stage Qc = Q[col_id] (includes pb1) into bufH (own rows)
#pragma unroll
  for (int i = 0; i < 4; ++i) {
    int q = lane + 64 * i; int r = q >> 4, cc = (q & 15) * 8; int e = ebase + r;
    bf16x8 res = {};
    if (e < NEDGES) res = *(const bf16x8*)(Qm + (size_t)eidx[NEDGES + e] * HDIM + cc);
    *(bf16x8*)lds_at(bufH, 16 * wv + r, cc * 2) = res;
  }
  __syncthreads();
  stage_weight(WT + 5 * 16384, wb, tid);   // pw1_b^T
  __syncthreads();
#pragma unroll
  for (int t = 0; t < 8; ++t) acc[t] = (f32x4){0.f, 0.f, 0.f, 0.f};
  wave_gemm(bufA, wb, acc, lane, wv);      // ne @ pw1_b
  // epilogue 3: h2 = relu(. + Qc); scatter-add to sums[row]
  int rid4[4];
#pragma unroll
  for (int j = 0; j < 4; ++j) {
    int e = ebase + 4 * (lane >> 4) + j;
    rid4[j] = (e < NEDGES) ? eidx[e] : -1;
  }
#pragma unroll
  for (int nt = 0; nt < 8; ++nt) {
    int col = nt * 16 + (lane & 15);
#pragma unroll
    for (int j = 0; j < 4; ++j) {
      if (rid4[j] >= 0) {
        int r = 4 * (lane >> 4) + j;
        float v = acc[nt][j] + bf2f(*lds_at(bufH, 16 * wv + r, col * 2));
        v = fmaxf(v, 0.0f);
        atomicAdd(&sums[(size_t)rid4[j] * HDIM + col], v);
      }
    }
  }
}

// ---------------- node final: agg -> gamma MLP -> + beta MLP ----------------
__global__ __launch_bounds__(256) void k_node(
    const float* __restrict__ x, const u16* __restrict__ WT,
    const float* __restrict__ sums, const float* __restrict__ counts,
    const float* __restrict__ pb2, const float* __restrict__ gb1,
    const float* __restrict__ gb2, const float* __restrict__ bb1,
    const float* __restrict__ bb2, float* __restrict__ dout) {
  __shared__ u16 smem[32768];
  u16* wb = smem; u16* bufA = smem + 16384; u16* bufH = smem + 24576;
  const int tid = threadIdx.x, lane = tid & 63, wv = tid >> 6;
  const int nbase = blockIdx.x * 64 + 16 * wv;
  // stage sums (own rows) -> bf16
#pragma unroll
  for (int i = 0; i < 8; ++i) {
    int q = lane + 64 * i; int r = q >> 5, c4 = q & 31; int n = nbase + r;
    float4 v = make_float4(0.f, 0.f, 0.f, 0.f);
    if (n < NNODES) v = *(const float4*)(sums + (size_t)n * HDIM + c4 * 4);
    u16x4 h = { f2bf(v.x), f2bf(v.y), f2bf(v.z), f2bf(v.w) };
    *(u16x4*)lds_at(bufA, 16 * wv + r, c4 * 8) = h;
  }
  stage_weight(WT + 6 * 16384, wb, tid);   // pw2^T
  __syncthreads();
  f32x4 acc[8] = {};
  wave_gemm(bufA, wb, acc, lane, wv);      // S @ pw2
  float cv[4];
#pragma unroll
  for (int j = 0; j < 4; ++j) {
    int n = nbase + 4 * (lane >> 4) + j;
    cv[j] = (n < NNODES) ? counts[n] : 0.0f;
  }
  // agg = cnt>0 ? S@pw2/cnt + pb2 : 0  -> bufH (bf16)
#pragma unroll
  for (int nt = 0; nt < 8; ++nt) {
    int col = nt * 16 + (lane & 15);
    float bias = pb2[col];
#pragma unroll
    for (int j = 0; j < 4; ++j) {
      int r = 4 * (lane >> 4) + j;
      float v = (cv[j] >= 1.0f) ? (acc[nt][j] / cv[j] + bias) : 0.0f;
      *lds_at(bufH, 16 * wv + r, col * 2) = f2bf(v);
    }
  }
  // restage x -> bufA (own rows already consumed)
#pragma unroll
  for (int i = 0; i < 8; ++i) {
    int q = lane + 64 * i; int r = q >> 5, c4 = q & 31; int n = nbase + r;
    float4 v = make_float4(0.f, 0.f, 0.f, 0.f);
    if (n < NNODES) v = *(const float4*)(x + (size_t)n * HDIM + c4 * 4);
    u16x4 h = { f2bf(v.x), f2bf(v.y), f2bf(v.z), f2bf(v.w) };
    *(u16x4*)lds_at(bufA, 16 * wv + r, c4 * 8) = h;
  }
  __syncthreads();
  stage_weight(WT + 7 * 16384, wb, tid);   // gw1_a^T
  __syncthreads();
  f32x4 acc2[8] = {};
  wave_gemm(bufA, wb, acc2, lane, wv);     // x @ gw1_a
  __syncthreads();
  stage_weight(WT + 8 * 16384, wb, tid);   // gw1_b^T
  __syncthreads();
  wave_gemm(bufH, wb, acc2, lane, wv);     // += agg @ gw1_b
#pragma unroll
  for (int nt = 0; nt < 8; ++nt) {
    int col = nt * 16 + (lane & 15);
    float bias = gb1[col];
#pragma unroll
    for (int j = 0; j < 4; ++j) {
      int r = 4 * (lane >> 4) + j;
      *lds_at(bufH, 16 * wv + r, col * 2) = f2bf(fmaxf(acc2[nt][j] + bias, 0.0f));
    }
  }
  __syncthreads();
  stage_weight(WT + 9 * 16384, wb, tid);   // gw2^T
  __syncthreads();
  f32x4 accX[8] = {};
  wave_gemm(bufH, wb, accX, lane, wv);     // x_new = h @ gw2 (+gb2 below)
#pragma unroll
  for (int nt = 0; nt < 8; ++nt) {
    int col = nt * 16 + (lane & 15);
    float bias = gb2[col];
#pragma unroll
    for (int j = 0; j < 4; ++j) {
      int r = 4 * (lane >> 4) + j;
      accX[nt][j] += bias;
      *lds_at(bufA, 16 * wv + r, col * 2) = f2bf(accX[nt][j]);
    }
  }
  __syncthreads();
  stage_weight(WT + 10 * 16384, wb, tid);  // bw1^T
  __syncthreads();
  f32x4 acc3[8] = {};
  wave_gemm(bufA, wb, acc3, lane, wv);
#pragma unroll
  for (int nt = 0; nt < 8; ++nt) {
    int col = nt * 16 + (lane & 15);
    float bias = bb1[col];
#pragma unroll
    for (int j = 0; j < 4; ++j) {
      int r = 4 * (lane >> 4) + j;
      *lds_at(bufH, 16 * wv + r, col * 2) = f2bf(fmaxf(acc3[nt][j] + bias, 0.0f));
    }
  }
  __syncthreads();
  stage_weight(WT + 11 * 16384, wb, tid);  // bw2^T
  __syncthreads();
  f32x4 acc4[8] = {};
  wave_gemm(bufH, wb, acc4, lane, wv);
#pragma unroll
  for (int nt = 0; nt < 8; ++nt) {
    int col = nt * 16 + (lane & 15);
    float bias = bb2[col];
#pragma unroll
    for (int j = 0; j < 4; ++j) {
      int n = nbase + 4 * (lane >> 4) + j;
      if (n < NNODES) dout[(size_t)n * HDIM + col] = accX[nt][j] + acc4[nt][j] + bias;
    }
  }
}

extern "C" void kernel_launch(void* const* d_in, const int* in_sizes, int n_in,
                              void* d_out, int out_size, void* d_ws, size_t ws_size,
                              hipStream_t stream) {
  (void)in_sizes; (void)n_in; (void)out_size; (void)ws_size;
  const float* x   = (const float*)d_in[0];
  const int* eidx  = (const int*)d_in[1];
  const float* attr= (const float*)d_in[2];
  const float* ew1 = (const float*)d_in[3];
  const float* eb1 = (const float*)d_in[4];
  const float* ew2 = (const float*)d_in[5];
  const float* eb2 = (const float*)d_in[6];
  const float* pw1 = (const float*)d_in[7];
  const float* pb1 = (const float*)d_in[8];
  const float* pw2 = (const float*)d_in[9];
  const float* pb2 = (const float*)d_in[10];
  const float* gw1 = (const float*)d_in[11];
  const float* gb1 = (const float*)d_in[12];
  const float* gw2 = (const float*)d_in[13];
  const float* gb2 = (const float*)d_in[14];
  const float* bw1 = (const float*)d_in[15];
  const float* bb1 = (const float*)d_in[16];
  const float* bw2 = (const float*)d_in[17];
  const float* bb2 = (const float*)d_in[18];

  char* ws = (char*)d_ws;
  u16* WT   = (u16*)(ws + WT_OFF);
  u16* P1   = (u16*)(ws + P1_OFF);
  u16* P2   = (u16*)(ws + P2_OFF);
  u16* Qm   = (u16*)(ws + Q_OFF);
  float* sums   = (float*)(ws + SUMS_OFF);
  float* counts = (float*)(ws + CNT_OFF);
  float* xnew_out = (float*)d_out;
  float* ne_out   = (float*)d_out + (size_t)NNODES * HDIM;

  hipMemsetAsync(ws + SUMS_OFF, 0, 51200000 + 400000, stream);
  k_prep<<<12, 256, 0, stream>>>(ew1, ew2, pw1, pw2, gw1, gw2, bw1, bw2, WT);
  k_node_pre<<<1563, 256, 0, stream>>>(x, WT, eb1, pb1, P1, P2, Qm);
  k_edge<<<7813, 256, 0, stream>>>(attr, eidx, WT, P1, P2, Qm, eb2, sums, counts, ne_out);
  k_node<<<1563, 256, 0, stream>>>(x, WT, sums, counts, pb2, gb1, gb2, bb1, bb2, xnew_out);
}